// Round 1
// baseline (3298.579 us; speedup 1.0000x reference)
//
#include <hip/hip_runtime.h>
#include <hip/hip_bf16.h>

// Problem constants (match reference)
constexpr int NN = 100000;
constexpr int EE = 1600000;
constexpr int CC = 128;       // C
constexpr float LN_EPS = 1e-5f;

// ---------------------------------------------------------------------------
// K1: per-node precompute
//   delta = tanh(relu(h@Wh1+bh1)@Wh2+bh2)        (N,3)
//   hWf   = h @ Wf[3:131,:]                      (N,128)
// 8 rows per block, 128 threads. Each thread owns one output column,
// keeps 8 row-accumulators; weights read once per k per block.
// ---------------------------------------------------------------------------
__global__ __launch_bounds__(128) void k_node(
    const float* __restrict__ h,
    const float* __restrict__ Wh1, const float* __restrict__ bh1,
    const float* __restrict__ Wh2, const float* __restrict__ bh2,
    const float* __restrict__ Wf,
    float* __restrict__ hWf, float* __restrict__ delta) {
  const int c = threadIdx.x;          // 0..127
  const int rbase = blockIdx.x * 8;
  __shared__ float hs[8][128];
  __shared__ float ts[8][128];

#pragma unroll
  for (int r = 0; r < 8; ++r)
    hs[r][c] = h[(long)(rbase + r) * CC + c];
  __syncthreads();

  float a1[8], a2[8];
#pragma unroll
  for (int r = 0; r < 8; ++r) { a1[r] = 0.f; a2[r] = 0.f; }

  for (int k = 0; k < 128; ++k) {
    const float w1 = Wh1[k * 128 + c];
    const float w2 = Wf[(k + 3) * 128 + c];
#pragma unroll
    for (int r = 0; r < 8; ++r) {
      a1[r] = fmaf(hs[r][k], w1, a1[r]);
      a2[r] = fmaf(hs[r][k], w2, a2[r]);
    }
  }

  const float b1 = bh1[c];
#pragma unroll
  for (int r = 0; r < 8; ++r) {
    ts[r][c] = fmaxf(a1[r] + b1, 0.f);
    hWf[(long)(rbase + r) * CC + c] = a2[r];
  }
  __syncthreads();

  if (c < 24) {                       // 8 rows x 3 dims
    const int r = c / 3, j = c % 3;
    float a = bh2[j];
    for (int k = 0; k < 128; ++k)
      a = fmaf(ts[r][k], Wh2[k * 3 + j], a);
    delta[(long)(rbase + r) * 3 + j] = tanhf(a);
  }
}

// ---------------------------------------------------------------------------
// K2: per-edge message + scatter-add
//   rel = pos[src]-pos[dst]+delta[dst]
//   m   = relu(rel@Wf[0:3] + hWf[src] + bf)
//   aggr[dst] += m    (f32 atomics)
// 8 edges per block (256 threads, 32 threads/edge, float4 per thread).
// ---------------------------------------------------------------------------
__global__ __launch_bounds__(256) void k_edge(
    const int* __restrict__ ei,          // (2,E): [0:E)=src, [E:2E)=dst
    const float* __restrict__ pos,
    const float* __restrict__ delta,
    const float* __restrict__ hWf,
    const float* __restrict__ Wf, const float* __restrict__ bf,
    float* __restrict__ aggr) {
  __shared__ int s_src[8];
  __shared__ int s_dst[8];
  __shared__ float s_rel[8][3];
  const int tid = threadIdx.x;
  const long ebase = (long)blockIdx.x * 8;

  if (tid < 8) {
    s_src[tid] = ei[ebase + tid];
    s_dst[tid] = ei[EE + ebase + tid];
  }
  __syncthreads();
  if (tid < 24) {
    const int e = tid / 3, d = tid % 3;
    const int s = s_src[e], dd = s_dst[e];
    s_rel[e][d] = pos[(long)s * 3 + d] - pos[(long)dd * 3 + d] + delta[(long)dd * 3 + d];
  }
  __syncthreads();

  const int e = tid >> 5;
  const int lane = tid & 31;
  const int src = s_src[e];
  const int dst = s_dst[e];
  const float r0 = s_rel[e][0], r1 = s_rel[e][1], r2 = s_rel[e][2];
  const int c = lane * 4;

  const float4 w0 = *reinterpret_cast<const float4*>(&Wf[0 * 128 + c]);
  const float4 w1 = *reinterpret_cast<const float4*>(&Wf[1 * 128 + c]);
  const float4 w2 = *reinterpret_cast<const float4*>(&Wf[2 * 128 + c]);
  const float4 bb = *reinterpret_cast<const float4*>(&bf[c]);
  const float4 hv = *reinterpret_cast<const float4*>(&hWf[(long)src * CC + c]);

  float4 m;
  m.x = fmaxf(fmaf(r0, w0.x, fmaf(r1, w1.x, fmaf(r2, w2.x, hv.x + bb.x))), 0.f);
  m.y = fmaxf(fmaf(r0, w0.y, fmaf(r1, w1.y, fmaf(r2, w2.y, hv.y + bb.y))), 0.f);
  m.z = fmaxf(fmaf(r0, w0.z, fmaf(r1, w1.z, fmaf(r2, w2.z, hv.z + bb.z))), 0.f);
  m.w = fmaxf(fmaf(r0, w0.w, fmaf(r1, w1.w, fmaf(r2, w2.w, hv.w + bb.w))), 0.f);

  float* ap = &aggr[(long)dst * CC + c];
  atomicAdd(ap + 0, m.x);
  atomicAdd(ap + 1, m.y);
  atomicAdd(ap + 2, m.z);
  atomicAdd(ap + 3, m.w);
}

// ---------------------------------------------------------------------------
// K3: out = leaky( relu(aggr@Wg1+bg1)@Wg2 + bg2 + h ), write to d_out,
//     plus per-column partial sums/sumsq into 64 partial slots.
// ---------------------------------------------------------------------------
__global__ __launch_bounds__(128) void k_out(
    const float* __restrict__ aggr,
    const float* __restrict__ Wg1, const float* __restrict__ bg1,
    const float* __restrict__ Wg2, const float* __restrict__ bg2,
    const float* __restrict__ h,
    float* __restrict__ out,
    float* __restrict__ psum, float* __restrict__ psumsq) {
  const int c = threadIdx.x;
  const int rbase = blockIdx.x * 8;
  __shared__ float as_[8][128];
  __shared__ float ts[8][128];

#pragma unroll
  for (int r = 0; r < 8; ++r)
    as_[r][c] = aggr[(long)(rbase + r) * CC + c];
  __syncthreads();

  float a[8];
#pragma unroll
  for (int r = 0; r < 8; ++r) a[r] = 0.f;
  for (int k = 0; k < 128; ++k) {
    const float w = Wg1[k * 128 + c];
#pragma unroll
    for (int r = 0; r < 8; ++r) a[r] = fmaf(as_[r][k], w, a[r]);
  }
  const float b1 = bg1[c];
#pragma unroll
  for (int r = 0; r < 8; ++r) ts[r][c] = fmaxf(a[r] + b1, 0.f);
  __syncthreads();

#pragma unroll
  for (int r = 0; r < 8; ++r) a[r] = 0.f;
  for (int k = 0; k < 128; ++k) {
    const float w = Wg2[k * 128 + c];
#pragma unroll
    for (int r = 0; r < 8; ++r) a[r] = fmaf(ts[r][k], w, a[r]);
  }

  const float b2 = bg2[c];
  float lsum = 0.f, lsq = 0.f;
#pragma unroll
  for (int r = 0; r < 8; ++r) {
    float o = a[r] + b2 + h[(long)(rbase + r) * CC + c];
    o = (o >= 0.f) ? o : 0.2f * o;
    out[(long)(rbase + r) * CC + c] = o;
    lsum += o;
    lsq = fmaf(o, o, lsq);
  }
  const int slot = blockIdx.x & 63;
  atomicAdd(&psum[slot * 128 + c], lsum);
  atomicAdd(&psumsq[slot * 128 + c], lsq);
}

// ---------------------------------------------------------------------------
// K4: reduce 64 partial slots -> mu, inv_std  (1 block, 128 threads)
// ---------------------------------------------------------------------------
__global__ __launch_bounds__(128) void k_stats(
    const float* __restrict__ psum, const float* __restrict__ psumsq,
    float* __restrict__ mu, float* __restrict__ inv) {
  const int c = threadIdx.x;
  float s = 0.f, q = 0.f;
  for (int i = 0; i < 64; ++i) {
    s += psum[i * 128 + c];
    q += psumsq[i * 128 + c];
  }
  const float m = s / (float)NN;
  const float v = q / (float)NN - m * m;
  mu[c] = m;
  inv[c] = rsqrtf(v + LN_EPS);
}

// ---------------------------------------------------------------------------
// K5: s = style@Ws + bs; gamma=s[:,:128], beta=s[:,128:]
//     out = gamma * (out-mu)*inv + beta     (in-place on d_out)
// 8 rows per block, 256 threads (one per s-column).
// ---------------------------------------------------------------------------
__global__ __launch_bounds__(256) void k_final(
    const float* __restrict__ style,
    const float* __restrict__ Ws, const float* __restrict__ bs,
    const float* __restrict__ mu, const float* __restrict__ inv,
    float* __restrict__ out) {
  const int t = threadIdx.x;          // 0..255
  const int rbase = blockIdx.x * 8;
  __shared__ float ss[8][128];
  __shared__ float sm[8][256];

#pragma unroll
  for (int i = 0; i < 4; ++i) {       // 1024 style elems / 256 threads
    const int idx = t + 256 * i;
    const int r = idx >> 7, k = idx & 127;
    ss[r][k] = style[(long)(rbase + r) * 128 + k];
  }
  __syncthreads();

  float a[8];
#pragma unroll
  for (int r = 0; r < 8; ++r) a[r] = 0.f;
  for (int k = 0; k < 128; ++k) {
    const float w = Ws[k * 256 + t];
#pragma unroll
    for (int r = 0; r < 8; ++r) a[r] = fmaf(ss[r][k], w, a[r]);
  }
  const float b = bs[t];
#pragma unroll
  for (int r = 0; r < 8; ++r) sm[r][t] = a[r] + b;
  __syncthreads();

#pragma unroll
  for (int i = 0; i < 4; ++i) {       // 1024 output elems / 256 threads
    const int idx = t + 256 * i;
    const int r = idx >> 7, c = idx & 127;
    const long g = (long)(rbase + r) * CC + c;
    const float o = out[g];
    out[g] = sm[r][c] * ((o - mu[c]) * inv[c]) + sm[r][128 + c];
  }
}

// ---------------------------------------------------------------------------
extern "C" void kernel_launch(void* const* d_in, const int* in_sizes, int n_in,
                              void* d_out, int out_size, void* d_ws, size_t ws_size,
                              hipStream_t stream) {
  const float* h     = (const float*)d_in[0];
  const float* pos   = (const float*)d_in[1];
  const float* style = (const float*)d_in[2];
  const int*   ei    = (const int*)  d_in[3];
  const float* Wh1   = (const float*)d_in[4];
  const float* bh1   = (const float*)d_in[5];
  const float* Wh2   = (const float*)d_in[6];
  const float* bh2   = (const float*)d_in[7];
  const float* Wf    = (const float*)d_in[8];
  const float* bf    = (const float*)d_in[9];
  const float* Wg1   = (const float*)d_in[10];
  const float* bg1   = (const float*)d_in[11];
  const float* Wg2   = (const float*)d_in[12];
  const float* bg2   = (const float*)d_in[13];
  const float* Ws    = (const float*)d_in[14];
  const float* bs    = (const float*)d_in[15];
  float* out = (float*)d_out;

  // workspace layout (floats)
  float* ws     = (float*)d_ws;
  float* hWf    = ws;                          // N*128
  float* aggr   = hWf + (long)NN * CC;         // N*128
  float* delta  = aggr + (long)NN * CC;        // N*3
  float* psum   = delta + (long)NN * 3;        // 64*128
  float* psumsq = psum + 64 * 128;             // 64*128
  float* mu     = psumsq + 64 * 128;           // 128
  float* inv    = mu + 128;                    // 128

  // zero the accumulators (ws is re-poisoned 0xAA before every timed call)
  hipMemsetAsync(aggr, 0, (size_t)NN * CC * sizeof(float), stream);
  hipMemsetAsync(psum, 0, (size_t)(64 * 128 * 2) * sizeof(float), stream);

  k_node<<<NN / 8, 128, 0, stream>>>(h, Wh1, bh1, Wh2, bh2, Wf, hWf, delta);
  k_edge<<<EE / 8, 256, 0, stream>>>(ei, pos, delta, hWf, Wf, bf, aggr);
  k_out<<<NN / 8, 128, 0, stream>>>(aggr, Wg1, bg1, Wg2, bg2, h, out, psum, psumsq);
  k_stats<<<1, 128, 0, stream>>>(psum, psumsq, mu, inv);
  k_final<<<NN / 8, 256, 0, stream>>>(style, Ws, bs, mu, inv, out);
}

// Round 2
// 1142.832 us; speedup vs baseline: 2.8863x; 2.8863x over previous
//
#include <hip/hip_runtime.h>
#include <hip/hip_bf16.h>

// Problem constants (match reference)
constexpr int NN = 100000;
constexpr int EE = 1600000;
constexpr int CC = 128;       // C
constexpr float LN_EPS = 1e-5f;

// ---------------------------------------------------------------------------
// K1: per-node precompute
//   delta = tanh(relu(h@Wh1+bh1)@Wh2+bh2)        (N,3)
//   hWf   = h @ Wf[3:131,:]                      (N,128)
// 8 rows per block, 128 threads.
// ---------------------------------------------------------------------------
__global__ __launch_bounds__(128) void k_node(
    const float* __restrict__ h,
    const float* __restrict__ Wh1, const float* __restrict__ bh1,
    const float* __restrict__ Wh2, const float* __restrict__ bh2,
    const float* __restrict__ Wf,
    float* __restrict__ hWf, float* __restrict__ delta) {
  const int c = threadIdx.x;          // 0..127
  const int rbase = blockIdx.x * 8;
  __shared__ float hs[8][128];
  __shared__ float ts[8][128];

#pragma unroll
  for (int r = 0; r < 8; ++r)
    hs[r][c] = h[(long)(rbase + r) * CC + c];
  __syncthreads();

  float a1[8], a2[8];
#pragma unroll
  for (int r = 0; r < 8; ++r) { a1[r] = 0.f; a2[r] = 0.f; }

  for (int k = 0; k < 128; ++k) {
    const float w1 = Wh1[k * 128 + c];
    const float w2 = Wf[(k + 3) * 128 + c];
#pragma unroll
    for (int r = 0; r < 8; ++r) {
      a1[r] = fmaf(hs[r][k], w1, a1[r]);
      a2[r] = fmaf(hs[r][k], w2, a2[r]);
    }
  }

  const float b1 = bh1[c];
#pragma unroll
  for (int r = 0; r < 8; ++r) {
    ts[r][c] = fmaxf(a1[r] + b1, 0.f);
    hWf[(long)(rbase + r) * CC + c] = a2[r];
  }
  __syncthreads();

  if (c < 24) {                       // 8 rows x 3 dims
    const int r = c / 3, j = c % 3;
    float a = bh2[j];
    for (int k = 0; k < 128; ++k)
      a = fmaf(ts[r][k], Wh2[k * 3 + j], a);
    delta[(long)(rbase + r) * 3 + j] = tanhf(a);
  }
}

// ---------------------------------------------------------------------------
// K2a: degree count — atomics on 4B counters only
// ---------------------------------------------------------------------------
__global__ __launch_bounds__(256) void k_count(
    const int* __restrict__ ei, int* __restrict__ deg) {
  const long e = (long)blockIdx.x * 256 + threadIdx.x;
  const int dst = ei[EE + e];
  atomicAdd(&deg[dst], 1);
}

// ---------------------------------------------------------------------------
// K2b: exclusive scan of deg (100000) -> off (100001) and cursor copy.
// Single block, 1024 threads, chunked; thread-0 serial scan of 1024 partials.
// ---------------------------------------------------------------------------
__global__ __launch_bounds__(1024) void k_scan(
    const int* __restrict__ deg, int* __restrict__ off, int* __restrict__ cursor) {
  const int tid = threadIdx.x;
  constexpr int CH = 98;              // 1024*98 >= 100000
  const int start = tid * CH;
  const int end = min(start + CH, NN);
  int sum = 0;
  for (int i = start; i < end; ++i) sum += deg[i];
  __shared__ int s[1024];
  s[tid] = sum;
  __syncthreads();
  if (tid == 0) {
    int run = 0;
    for (int i = 0; i < 1024; ++i) { int v = s[i]; s[i] = run; run += v; }
  }
  __syncthreads();
  int run = s[tid];
  for (int i = start; i < end; ++i) {
    off[i] = run; cursor[i] = run; run += deg[i];
  }
  if (tid == 1023) off[NN] = EE;
}

// ---------------------------------------------------------------------------
// K2c: scatter edges into dst-bins (store src index)
// ---------------------------------------------------------------------------
__global__ __launch_bounds__(256) void k_scatter(
    const int* __restrict__ ei, int* __restrict__ cursor, int* __restrict__ ebin) {
  const long e = (long)blockIdx.x * 256 + threadIdx.x;
  const int src = ei[e];
  const int dst = ei[EE + e];
  const int p = atomicAdd(&cursor[dst], 1);
  ebin[p] = src;
}

// ---------------------------------------------------------------------------
// K2d: atomic-free aggregation. One block (128 threads) per dst node:
//   aggr[n] = sum_{edges e: dst=n} relu( rel_e @ Wf[0:3] + hWf[src_e] + bf )
//   rel_e = pos[src_e] + (delta[n] - pos[n])
// ---------------------------------------------------------------------------
__global__ __launch_bounds__(128) void k_aggr(
    const int* __restrict__ off, const int* __restrict__ ebin,
    const float* __restrict__ pos, const float* __restrict__ delta,
    const float* __restrict__ hWf,
    const float* __restrict__ Wf, const float* __restrict__ bf,
    float* __restrict__ aggr) {
  const int n = blockIdx.x;
  const int c = threadIdx.x;
  __shared__ float base[3];
  __shared__ int s_src[128];
  __shared__ float s_rel[128][3];

  if (c < 3) base[c] = delta[(long)n * 3 + c] - pos[(long)n * 3 + c];
  const int s = off[n], e = off[n + 1];

  const float w0 = Wf[0 * 128 + c];
  const float w1 = Wf[1 * 128 + c];
  const float w2 = Wf[2 * 128 + c];
  const float bb = bf[c];
  float acc = 0.f;
  __syncthreads();

  for (int js = s; js < e; js += 128) {
    const int cnt = min(128, e - js);
    if (c < cnt) {
      const int src = ebin[js + c];
      s_src[c] = src;
      s_rel[c][0] = pos[(long)src * 3 + 0] + base[0];
      s_rel[c][1] = pos[(long)src * 3 + 1] + base[1];
      s_rel[c][2] = pos[(long)src * 3 + 2] + base[2];
    }
    __syncthreads();
#pragma unroll 4
    for (int j = 0; j < cnt; ++j) {
      const int src = s_src[j];
      const float hv = hWf[(long)src * CC + c];
      const float m = fmaf(s_rel[j][0], w0,
                      fmaf(s_rel[j][1], w1,
                      fmaf(s_rel[j][2], w2, hv + bb)));
      acc += fmaxf(m, 0.f);
    }
    __syncthreads();
  }
  aggr[(long)n * CC + c] = acc;
}

// ---------------------------------------------------------------------------
// K3: out = leaky( relu(aggr@Wg1+bg1)@Wg2 + bg2 + h ), write to d_out,
//     plus per-column partial sums/sumsq into 64 partial slots.
// ---------------------------------------------------------------------------
__global__ __launch_bounds__(128) void k_out(
    const float* __restrict__ aggr,
    const float* __restrict__ Wg1, const float* __restrict__ bg1,
    const float* __restrict__ Wg2, const float* __restrict__ bg2,
    const float* __restrict__ h,
    float* __restrict__ out,
    float* __restrict__ psum, float* __restrict__ psumsq) {
  const int c = threadIdx.x;
  const int rbase = blockIdx.x * 8;
  __shared__ float as_[8][128];
  __shared__ float ts[8][128];

#pragma unroll
  for (int r = 0; r < 8; ++r)
    as_[r][c] = aggr[(long)(rbase + r) * CC + c];
  __syncthreads();

  float a[8];
#pragma unroll
  for (int r = 0; r < 8; ++r) a[r] = 0.f;
  for (int k = 0; k < 128; ++k) {
    const float w = Wg1[k * 128 + c];
#pragma unroll
    for (int r = 0; r < 8; ++r) a[r] = fmaf(as_[r][k], w, a[r]);
  }
  const float b1 = bg1[c];
#pragma unroll
  for (int r = 0; r < 8; ++r) ts[r][c] = fmaxf(a[r] + b1, 0.f);
  __syncthreads();

#pragma unroll
  for (int r = 0; r < 8; ++r) a[r] = 0.f;
  for (int k = 0; k < 128; ++k) {
    const float w = Wg2[k * 128 + c];
#pragma unroll
    for (int r = 0; r < 8; ++r) a[r] = fmaf(ts[r][k], w, a[r]);
  }

  const float b2 = bg2[c];
  float lsum = 0.f, lsq = 0.f;
#pragma unroll
  for (int r = 0; r < 8; ++r) {
    float o = a[r] + b2 + h[(long)(rbase + r) * CC + c];
    o = (o >= 0.f) ? o : 0.2f * o;
    out[(long)(rbase + r) * CC + c] = o;
    lsum += o;
    lsq = fmaf(o, o, lsq);
  }
  const int slot = blockIdx.x & 63;
  atomicAdd(&psum[slot * 128 + c], lsum);
  atomicAdd(&psumsq[slot * 128 + c], lsq);
}

// ---------------------------------------------------------------------------
// K4: reduce 64 partial slots -> mu, inv_std  (1 block, 128 threads)
// ---------------------------------------------------------------------------
__global__ __launch_bounds__(128) void k_stats(
    const float* __restrict__ psum, const float* __restrict__ psumsq,
    float* __restrict__ mu, float* __restrict__ inv) {
  const int c = threadIdx.x;
  float s = 0.f, q = 0.f;
  for (int i = 0; i < 64; ++i) {
    s += psum[i * 128 + c];
    q += psumsq[i * 128 + c];
  }
  const float m = s / (float)NN;
  const float v = q / (float)NN - m * m;
  mu[c] = m;
  inv[c] = rsqrtf(v + LN_EPS);
}

// ---------------------------------------------------------------------------
// K5: s = style@Ws + bs; gamma=s[:,:128], beta=s[:,128:]
//     out = gamma * (out-mu)*inv + beta     (in-place on d_out)
// ---------------------------------------------------------------------------
__global__ __launch_bounds__(256) void k_final(
    const float* __restrict__ style,
    const float* __restrict__ Ws, const float* __restrict__ bs,
    const float* __restrict__ mu, const float* __restrict__ inv,
    float* __restrict__ out) {
  const int t = threadIdx.x;          // 0..255
  const int rbase = blockIdx.x * 8;
  __shared__ float ss[8][128];
  __shared__ float sm[8][256];

#pragma unroll
  for (int i = 0; i < 4; ++i) {       // 1024 style elems / 256 threads
    const int idx = t + 256 * i;
    const int r = idx >> 7, k = idx & 127;
    ss[r][k] = style[(long)(rbase + r) * 128 + k];
  }
  __syncthreads();

  float a[8];
#pragma unroll
  for (int r = 0; r < 8; ++r) a[r] = 0.f;
  for (int k = 0; k < 128; ++k) {
    const float w = Ws[k * 256 + t];
#pragma unroll
    for (int r = 0; r < 8; ++r) a[r] = fmaf(ss[r][k], w, a[r]);
  }
  const float b = bs[t];
#pragma unroll
  for (int r = 0; r < 8; ++r) sm[r][t] = a[r] + b;
  __syncthreads();

#pragma unroll
  for (int i = 0; i < 4; ++i) {       // 1024 output elems / 256 threads
    const int idx = t + 256 * i;
    const int r = idx >> 7, c = idx & 127;
    const long g = (long)(rbase + r) * CC + c;
    const float o = out[g];
    out[g] = sm[r][c] * ((o - mu[c]) * inv[c]) + sm[r][128 + c];
  }
}

// ---------------------------------------------------------------------------
extern "C" void kernel_launch(void* const* d_in, const int* in_sizes, int n_in,
                              void* d_out, int out_size, void* d_ws, size_t ws_size,
                              hipStream_t stream) {
  const float* h     = (const float*)d_in[0];
  const float* pos   = (const float*)d_in[1];
  const float* style = (const float*)d_in[2];
  const int*   ei    = (const int*)  d_in[3];
  const float* Wh1   = (const float*)d_in[4];
  const float* bh1   = (const float*)d_in[5];
  const float* Wh2   = (const float*)d_in[6];
  const float* bh2   = (const float*)d_in[7];
  const float* Wf    = (const float*)d_in[8];
  const float* bf    = (const float*)d_in[9];
  const float* Wg1   = (const float*)d_in[10];
  const float* bg1   = (const float*)d_in[11];
  const float* Wg2   = (const float*)d_in[12];
  const float* bg2   = (const float*)d_in[13];
  const float* Ws    = (const float*)d_in[14];
  const float* bs    = (const float*)d_in[15];
  float* out = (float*)d_out;

  // workspace layout (floats / ints)
  float* ws     = (float*)d_ws;
  float* hWf    = ws;                          // N*128
  float* aggr   = hWf + (long)NN * CC;         // N*128
  float* delta  = aggr + (long)NN * CC;        // N*3
  float* psum   = delta + (long)NN * 3;        // 64*128
  float* psumsq = psum + 64 * 128;             // 64*128
  float* mu     = psumsq + 64 * 128;           // 128
  float* inv    = mu + 128;                    // 128
  int*   deg    = (int*)(inv + 128);           // N
  int*   off    = deg + NN;                    // N+1
  int*   cursor = off + NN + 1;                // N
  int*   ebin   = cursor + NN;                 // E

  hipMemsetAsync(deg, 0, (size_t)NN * sizeof(int), stream);
  hipMemsetAsync(psum, 0, (size_t)(64 * 128 * 2) * sizeof(float), stream);

  k_node<<<NN / 8, 128, 0, stream>>>(h, Wh1, bh1, Wh2, bh2, Wf, hWf, delta);
  k_count<<<EE / 256, 256, 0, stream>>>(ei, deg);
  k_scan<<<1, 1024, 0, stream>>>(deg, off, cursor);
  k_scatter<<<EE / 256, 256, 0, stream>>>(ei, cursor, ebin);
  k_aggr<<<NN, 128, 0, stream>>>(off, ebin, pos, delta, hWf, Wf, bf, aggr);
  k_out<<<NN / 8, 128, 0, stream>>>(aggr, Wg1, bg1, Wg2, bg2, h, out, psum, psumsq);
  k_stats<<<1, 128, 0, stream>>>(psum, psumsq, mu, inv);
  k_final<<<NN / 8, 256, 0, stream>>>(style, Ws, bs, mu, inv, out);
}

// Round 5
// 872.049 us; speedup vs baseline: 3.7826x; 1.3105x over previous
//
#include <hip/hip_runtime.h>
#include <hip/hip_bf16.h>

// Problem constants (match reference)
constexpr int NN = 100000;
constexpr int EE = 1600000;
constexpr int CC = 128;       // C
constexpr float LN_EPS = 1e-5f;

constexpr int SCAN_CHUNK = 1024;                       // elems per scan block
constexpr int SCAN_NBLK = (NN + SCAN_CHUNK - 1) / SCAN_CHUNK;  // 98

// ---------------------------------------------------------------------------
// K1: per-node precompute
//   delta = tanh(relu(h@Wh1+bh1)@Wh2+bh2)        (N,3)
//   hWf   = h @ Wf[3:131,:]                      (N,128)
// ---------------------------------------------------------------------------
__global__ __launch_bounds__(128) void k_node(
    const float* __restrict__ h,
    const float* __restrict__ Wh1, const float* __restrict__ bh1,
    const float* __restrict__ Wh2, const float* __restrict__ bh2,
    const float* __restrict__ Wf,
    float* __restrict__ hWf, float* __restrict__ delta) {
  const int c = threadIdx.x;          // 0..127
  const int rbase = blockIdx.x * 8;
  __shared__ float hs[8][128];
  __shared__ float ts[8][128];

#pragma unroll
  for (int r = 0; r < 8; ++r)
    hs[r][c] = h[(long)(rbase + r) * CC + c];
  __syncthreads();

  float a1[8], a2[8];
#pragma unroll
  for (int r = 0; r < 8; ++r) { a1[r] = 0.f; a2[r] = 0.f; }

  for (int k = 0; k < 128; ++k) {
    const float w1 = Wh1[k * 128 + c];
    const float w2 = Wf[(k + 3) * 128 + c];
#pragma unroll
    for (int r = 0; r < 8; ++r) {
      a1[r] = fmaf(hs[r][k], w1, a1[r]);
      a2[r] = fmaf(hs[r][k], w2, a2[r]);
    }
  }

  const float b1 = bh1[c];
#pragma unroll
  for (int r = 0; r < 8; ++r) {
    ts[r][c] = fmaxf(a1[r] + b1, 0.f);
    hWf[(long)(rbase + r) * CC + c] = a2[r];
  }
  __syncthreads();

  if (c < 24) {                       // 8 rows x 3 dims
    const int r = c / 3, j = c % 3;
    float a = bh2[j];
    for (int k = 0; k < 128; ++k)
      a = fmaf(ts[r][k], Wh2[k * 3 + j], a);
    delta[(long)(rbase + r) * 3 + j] = tanhf(a);
  }
}

// ---------------------------------------------------------------------------
// K2a: degree count — atomics on 4B counters only
// ---------------------------------------------------------------------------
__global__ __launch_bounds__(256) void k_count(
    const int* __restrict__ ei, int* __restrict__ deg) {
  const long e = (long)blockIdx.x * 256 + threadIdx.x;
  const int dst = ei[EE + e];
  atomicAdd(&deg[dst], 1);
}

// ---------------------------------------------------------------------------
// K2b-1: per-block scan. 98 blocks x 256 threads x 4 elems.
//   off[i] = exclusive prefix of deg within block; bsum[b] = block total.
// ---------------------------------------------------------------------------
__global__ __launch_bounds__(256) void k_scan1(
    const int* __restrict__ deg, int* __restrict__ off, int* __restrict__ bsum) {
  const int t = threadIdx.x;
  const int base = blockIdx.x * SCAN_CHUNK + t * 4;
  int4 v = make_int4(0, 0, 0, 0);
  if (base + 3 < NN) {
    v = *reinterpret_cast<const int4*>(&deg[base]);
  } else {
    if (base + 0 < NN) v.x = deg[base + 0];
    if (base + 1 < NN) v.y = deg[base + 1];
    if (base + 2 < NN) v.z = deg[base + 2];
  }
  const int tsum = v.x + v.y + v.z + v.w;

  // inclusive shuffle-scan within each 64-lane wave
  int x = tsum;
#pragma unroll
  for (int d = 1; d < 64; d <<= 1) {
    const int y = __shfl_up(x, d, 64);
    if ((t & 63) >= d) x += y;
  }
  __shared__ int wsum[4];
  if ((t & 63) == 63) wsum[t >> 6] = x;
  __syncthreads();
  int woff = 0;
  for (int w = 0; w < (t >> 6); ++w) woff += wsum[w];
  const int excl = x - tsum + woff;   // exclusive prefix of this thread's 4-chunk

  if (base + 0 < NN) off[base + 0] = excl;
  if (base + 1 < NN) off[base + 1] = excl + v.x;
  if (base + 2 < NN) off[base + 2] = excl + v.x + v.y;
  if (base + 3 < NN) off[base + 3] = excl + v.x + v.y + v.z;
  if (t == 255) bsum[blockIdx.x] = wsum[0] + wsum[1] + wsum[2] + wsum[3];
}

// ---------------------------------------------------------------------------
// K2b-2: exclusive scan of the 98 block sums (in place). 1 block, 128 thr.
// ---------------------------------------------------------------------------
__global__ __launch_bounds__(128) void k_scan2(int* __restrict__ bsum) {
  const int t = threadIdx.x;
  const int v = (t < SCAN_NBLK) ? bsum[t] : 0;
  int x = v;
#pragma unroll
  for (int d = 1; d < 64; d <<= 1) {
    const int y = __shfl_up(x, d, 64);
    if ((t & 63) >= d) x += y;
  }
  __shared__ int ws[2];
  if ((t & 63) == 63) ws[t >> 6] = x;
  __syncthreads();
  const int excl = x - v + ((t >= 64) ? ws[0] : 0);
  if (t < SCAN_NBLK) bsum[t] = excl;
}

// ---------------------------------------------------------------------------
// K2b-3: add block offsets; emit final off + cursor copy; off[NN]=EE.
// ---------------------------------------------------------------------------
__global__ __launch_bounds__(256) void k_scan3(
    const int* __restrict__ bsum, int* __restrict__ off, int* __restrict__ cursor) {
  const int t = threadIdx.x;
  const int base = blockIdx.x * SCAN_CHUNK + t * 4;
  const int add = bsum[blockIdx.x];
  if (base + 3 < NN) {
    int4 v = *reinterpret_cast<const int4*>(&off[base]);
    v.x += add; v.y += add; v.z += add; v.w += add;
    *reinterpret_cast<int4*>(&off[base]) = v;
    *reinterpret_cast<int4*>(&cursor[base]) = v;
  } else {
#pragma unroll
    for (int i = 0; i < 4; ++i)
      if (base + i < NN) {
        const int v = off[base + i] + add;
        off[base + i] = v;
        cursor[base + i] = v;
      }
  }
  if (blockIdx.x == 0 && t == 0) off[NN] = EE;
}

// ---------------------------------------------------------------------------
// K2c: scatter edges into dst-bins (store src index)
// ---------------------------------------------------------------------------
__global__ __launch_bounds__(256) void k_scatter(
    const int* __restrict__ ei, int* __restrict__ cursor, int* __restrict__ ebin) {
  const long e = (long)blockIdx.x * 256 + threadIdx.x;
  const int src = ei[e];
  const int dst = ei[EE + e];
  const int p = atomicAdd(&cursor[dst], 1);
  ebin[p] = src;
}

// ---------------------------------------------------------------------------
// K2d: atomic-free aggregation. One block (128 threads) per dst node:
//   aggr[n] = sum_{edges e: dst=n} relu( rel_e @ Wf[0:3] + hWf[src_e] + bf )
//   rel_e = pos[src_e] + (delta[n] - pos[n])
// ---------------------------------------------------------------------------
__global__ __launch_bounds__(128) void k_aggr(
    const int* __restrict__ off, const int* __restrict__ ebin,
    const float* __restrict__ pos, const float* __restrict__ delta,
    const float* __restrict__ hWf,
    const float* __restrict__ Wf, const float* __restrict__ bf,
    float* __restrict__ aggr) {
  const int n = blockIdx.x;
  const int c = threadIdx.x;
  __shared__ float base[3];
  __shared__ int s_src[128];
  __shared__ float s_rel[128][3];

  if (c < 3) base[c] = delta[(long)n * 3 + c] - pos[(long)n * 3 + c];
  const int s = off[n], e = off[n + 1];

  const float w0 = Wf[0 * 128 + c];
  const float w1 = Wf[1 * 128 + c];
  const float w2 = Wf[2 * 128 + c];
  const float bb = bf[c];
  float acc = 0.f;
  __syncthreads();

  for (int js = s; js < e; js += 128) {
    const int cnt = min(128, e - js);
    if (c < cnt) {
      const int src = ebin[js + c];
      s_src[c] = src;
      s_rel[c][0] = pos[(long)src * 3 + 0] + base[0];
      s_rel[c][1] = pos[(long)src * 3 + 1] + base[1];
      s_rel[c][2] = pos[(long)src * 3 + 2] + base[2];
    }
    __syncthreads();
#pragma unroll 4
    for (int j = 0; j < cnt; ++j) {
      const int src = s_src[j];
      const float hv = hWf[(long)src * CC + c];
      const float m = fmaf(s_rel[j][0], w0,
                      fmaf(s_rel[j][1], w1,
                      fmaf(s_rel[j][2], w2, hv + bb)));
      acc += fmaxf(m, 0.f);
    }
    __syncthreads();
  }
  aggr[(long)n * CC + c] = acc;
}

// ---------------------------------------------------------------------------
// K3: out = leaky( relu(aggr@Wg1+bg1)@Wg2 + bg2 + h ), write to d_out,
//     plus per-column partial sums/sumsq into 64 partial slots.
// ---------------------------------------------------------------------------
__global__ __launch_bounds__(128) void k_out(
    const float* __restrict__ aggr,
    const float* __restrict__ Wg1, const float* __restrict__ bg1,
    const float* __restrict__ Wg2, const float* __restrict__ bg2,
    const float* __restrict__ h,
    float* __restrict__ out,
    float* __restrict__ psum, float* __restrict__ psumsq) {
  const int c = threadIdx.x;
  const int rbase = blockIdx.x * 8;
  __shared__ float as_[8][128];
  __shared__ float ts[8][128];

#pragma unroll
  for (int r = 0; r < 8; ++r)
    as_[r][c] = aggr[(long)(rbase + r) * CC + c];
  __syncthreads();

  float a[8];
#pragma unroll
  for (int r = 0; r < 8; ++r) a[r] = 0.f;
  for (int k = 0; k < 128; ++k) {
    const float w = Wg1[k * 128 + c];
#pragma unroll
    for (int r = 0; r < 8; ++r) a[r] = fmaf(as_[r][k], w, a[r]);
  }
  const float b1 = bg1[c];
#pragma unroll
  for (int r = 0; r < 8; ++r) ts[r][c] = fmaxf(a[r] + b1, 0.f);
  __syncthreads();

#pragma unroll
  for (int r = 0; r < 8; ++r) a[r] = 0.f;
  for (int k = 0; k < 128; ++k) {
    const float w = Wg2[k * 128 + c];
#pragma unroll
    for (int r = 0; r < 8; ++r) a[r] = fmaf(ts[r][k], w, a[r]);
  }

  const float b2 = bg2[c];
  float lsum = 0.f, lsq = 0.f;
#pragma unroll
  for (int r = 0; r < 8; ++r) {
    float o = a[r] + b2 + h[(long)(rbase + r) * CC + c];
    o = (o >= 0.f) ? o : 0.2f * o;
    out[(long)(rbase + r) * CC + c] = o;
    lsum += o;
    lsq = fmaf(o, o, lsq);
  }
  const int slot = blockIdx.x & 63;
  atomicAdd(&psum[slot * 128 + c], lsum);
  atomicAdd(&psumsq[slot * 128 + c], lsq);
}

// ---------------------------------------------------------------------------
// K4: reduce 64 partial slots -> mu, inv_std  (1 block, 128 threads)
// ---------------------------------------------------------------------------
__global__ __launch_bounds__(128) void k_stats(
    const float* __restrict__ psum, const float* __restrict__ psumsq,
    float* __restrict__ mu, float* __restrict__ inv) {
  const int c = threadIdx.x;
  float s = 0.f, q = 0.f;
  for (int i = 0; i < 64; ++i) {
    s += psum[i * 128 + c];
    q += psumsq[i * 128 + c];
  }
  const float m = s / (float)NN;
  const float v = q / (float)NN - m * m;
  mu[c] = m;
  inv[c] = rsqrtf(v + LN_EPS);
}

// ---------------------------------------------------------------------------
// K5: s = style@Ws + bs; gamma=s[:,:128], beta=s[:,128:]
//     out = gamma * (out-mu)*inv + beta     (in-place on d_out)
// ---------------------------------------------------------------------------
__global__ __launch_bounds__(256) void k_final(
    const float* __restrict__ style,
    const float* __restrict__ Ws, const float* __restrict__ bs,
    const float* __restrict__ mu, const float* __restrict__ inv,
    float* __restrict__ out) {
  const int t = threadIdx.x;          // 0..255
  const int rbase = blockIdx.x * 8;
  __shared__ float ss[8][128];
  __shared__ float sm[8][256];

#pragma unroll
  for (int i = 0; i < 4; ++i) {       // 1024 style elems / 256 threads
    const int idx = t + 256 * i;
    const int r = idx >> 7, k = idx & 127;
    ss[r][k] = style[(long)(rbase + r) * 128 + k];
  }
  __syncthreads();

  float a[8];
#pragma unroll
  for (int r = 0; r < 8; ++r) a[r] = 0.f;
  for (int k = 0; k < 128; ++k) {
    const float w = Ws[k * 256 + t];
#pragma unroll
    for (int r = 0; r < 8; ++r) a[r] = fmaf(ss[r][k], w, a[r]);
  }
  const float b = bs[t];
#pragma unroll
  for (int r = 0; r < 8; ++r) sm[r][t] = a[r] + b;
  __syncthreads();

#pragma unroll
  for (int i = 0; i < 4; ++i) {       // 1024 output elems / 256 threads
    const int idx = t + 256 * i;
    const int r = idx >> 7, c = idx & 127;
    const long g = (long)(rbase + r) * CC + c;
    const float o = out[g];
    out[g] = sm[r][c] * ((o - mu[c]) * inv[c]) + sm[r][128 + c];
  }
}

// ---------------------------------------------------------------------------
extern "C" void kernel_launch(void* const* d_in, const int* in_sizes, int n_in,
                              void* d_out, int out_size, void* d_ws, size_t ws_size,
                              hipStream_t stream) {
  const float* h     = (const float*)d_in[0];
  const float* pos   = (const float*)d_in[1];
  const float* style = (const float*)d_in[2];
  const int*   ei    = (const int*)  d_in[3];
  const float* Wh1   = (const float*)d_in[4];
  const float* bh1   = (const float*)d_in[5];
  const float* Wh2   = (const float*)d_in[6];
  const float* bh2   = (const float*)d_in[7];
  const float* Wf    = (const float*)d_in[8];
  const float* bf    = (const float*)d_in[9];
  const float* Wg1   = (const float*)d_in[10];
  const float* bg1   = (const float*)d_in[11];
  const float* Wg2   = (const float*)d_in[12];
  const float* bg2   = (const float*)d_in[13];
  const float* Ws    = (const float*)d_in[14];
  const float* bs    = (const float*)d_in[15];
  float* out = (float*)d_out;

  // workspace layout (floats / ints) — all segments 16B-aligned
  float* ws     = (float*)d_ws;
  float* hWf    = ws;                          // N*128
  float* aggr   = hWf + (long)NN * CC;         // N*128
  float* delta  = aggr + (long)NN * CC;        // N*3
  float* psum   = delta + (long)NN * 3;        // 64*128
  float* psumsq = psum + 64 * 128;             // 64*128
  float* mu     = psumsq + 64 * 128;           // 128
  float* inv    = mu + 128;                    // 128
  int*   deg    = (int*)(inv + 128);           // N
  int*   off    = deg + NN;                    // N+1 (padded to N+4)
  int*   cursor = off + NN + 4;                // N
  int*   ebin   = cursor + NN;                 // E
  int*   bsum   = ebin + EE;                   // SCAN_NBLK (98), pad 128

  hipMemsetAsync(deg, 0, (size_t)NN * sizeof(int), stream);
  hipMemsetAsync(psum, 0, (size_t)(64 * 128 * 2) * sizeof(float), stream);

  k_node<<<NN / 8, 128, 0, stream>>>(h, Wh1, bh1, Wh2, bh2, Wf, hWf, delta);
  k_count<<<EE / 256, 256, 0, stream>>>(ei, deg);
  k_scan1<<<SCAN_NBLK, 256, 0, stream>>>(deg, off, bsum);
  k_scan2<<<1, 128, 0, stream>>>(bsum);
  k_scan3<<<SCAN_NBLK, 256, 0, stream>>>(bsum, off, cursor);
  k_scatter<<<EE / 256, 256, 0, stream>>>(ei, cursor, ebin);
  k_aggr<<<NN, 128, 0, stream>>>(off, ebin, pos, delta, hWf, Wf, bf, aggr);
  k_out<<<NN / 8, 128, 0, stream>>>(aggr, Wg1, bg1, Wg2, bg2, h, out, psum, psumsq);
  k_stats<<<1, 128, 0, stream>>>(psum, psumsq, mu, inv);
  k_final<<<NN / 8, 256, 0, stream>>>(style, Ws, bs, mu, inv, out);
}

// Round 6
// 854.799 us; speedup vs baseline: 3.8589x; 1.0202x over previous
//
#include <hip/hip_runtime.h>
#include <hip/hip_bf16.h>

// Problem constants (match reference)
constexpr int NN = 100000;
constexpr int EE = 1600000;
constexpr int CC = 128;       // C
constexpr float LN_EPS = 1e-5f;

constexpr int SCAN_CHUNK = 1024;                       // elems per scan block
constexpr int SCAN_NBLK = (NN + SCAN_CHUNK - 1) / SCAN_CHUNK;  // 98

// ---------------------------------------------------------------------------
// K1: per-node precompute
//   delta = tanh(relu(h@Wh1+bh1)@Wh2+bh2)        (N,3)
//   hWf   = h @ Wf[3:131,:]                      (N,128)
// 16 rows/block, 128 threads (1 col each). A-operand read as broadcast
// ds_read_b128 (4 k-steps per issue) -> FMA-bound, not LDS-issue-bound.
// ---------------------------------------------------------------------------
__global__ __launch_bounds__(128) void k_node(
    const float* __restrict__ h,
    const float* __restrict__ Wh1, const float* __restrict__ bh1,
    const float* __restrict__ Wh2, const float* __restrict__ bh2,
    const float* __restrict__ Wf,
    float* __restrict__ hWf, float* __restrict__ delta) {
  const int c = threadIdx.x;          // 0..127
  const int rbase = blockIdx.x * 16;
  __shared__ float hs[16][128];       // float4-read: keep unpadded (16B align)
  __shared__ float ts[16][129];       // scalar-read in delta tail: pad -> bank (r+k)%32

#pragma unroll
  for (int r = 0; r < 16; ++r)
    hs[r][c] = h[(long)(rbase + r) * CC + c];
  __syncthreads();

  float a1[16], a2[16];
#pragma unroll
  for (int r = 0; r < 16; ++r) { a1[r] = 0.f; a2[r] = 0.f; }

  for (int k = 0; k < 128; k += 4) {
    float w1[4], w2[4];
#pragma unroll
    for (int q = 0; q < 4; ++q) {
      w1[q] = Wh1[(k + q) * 128 + c];
      w2[q] = Wf[(k + q + 3) * 128 + c];
    }
#pragma unroll
    for (int r = 0; r < 16; ++r) {
      const float4 hv = *reinterpret_cast<const float4*>(&hs[r][k]);
      a1[r] = fmaf(hv.x, w1[0], a1[r]);
      a1[r] = fmaf(hv.y, w1[1], a1[r]);
      a1[r] = fmaf(hv.z, w1[2], a1[r]);
      a1[r] = fmaf(hv.w, w1[3], a1[r]);
      a2[r] = fmaf(hv.x, w2[0], a2[r]);
      a2[r] = fmaf(hv.y, w2[1], a2[r]);
      a2[r] = fmaf(hv.z, w2[2], a2[r]);
      a2[r] = fmaf(hv.w, w2[3], a2[r]);
    }
  }

  const float b1 = bh1[c];
#pragma unroll
  for (int r = 0; r < 16; ++r) {
    ts[r][c] = fmaxf(a1[r] + b1, 0.f);
    hWf[(long)(rbase + r) * CC + c] = a2[r];
  }
  __syncthreads();

  if (c < 48) {                       // 16 rows x 3 dims
    const int r = c / 3, j = c % 3;
    float a = bh2[j];
    for (int k = 0; k < 128; ++k)
      a = fmaf(ts[r][k], Wh2[k * 3 + j], a);
    delta[(long)(rbase + r) * 3 + j] = tanhf(a);
  }
}

// ---------------------------------------------------------------------------
// K2a: degree count — atomics on 4B counters only
// ---------------------------------------------------------------------------
__global__ __launch_bounds__(256) void k_count(
    const int* __restrict__ ei, int* __restrict__ deg) {
  const long e = (long)blockIdx.x * 256 + threadIdx.x;
  const int dst = ei[EE + e];
  atomicAdd(&deg[dst], 1);
}

// ---------------------------------------------------------------------------
// K2b-1: per-block scan. 98 blocks x 256 threads x 4 elems.
// ---------------------------------------------------------------------------
__global__ __launch_bounds__(256) void k_scan1(
    const int* __restrict__ deg, int* __restrict__ off, int* __restrict__ bsum) {
  const int t = threadIdx.x;
  const int base = blockIdx.x * SCAN_CHUNK + t * 4;
  int4 v = make_int4(0, 0, 0, 0);
  if (base + 3 < NN) {
    v = *reinterpret_cast<const int4*>(&deg[base]);
  } else {
    if (base + 0 < NN) v.x = deg[base + 0];
    if (base + 1 < NN) v.y = deg[base + 1];
    if (base + 2 < NN) v.z = deg[base + 2];
  }
  const int tsum = v.x + v.y + v.z + v.w;

  int x = tsum;
#pragma unroll
  for (int d = 1; d < 64; d <<= 1) {
    const int y = __shfl_up(x, d, 64);
    if ((t & 63) >= d) x += y;
  }
  __shared__ int wsum[4];
  if ((t & 63) == 63) wsum[t >> 6] = x;
  __syncthreads();
  int woff = 0;
  for (int w = 0; w < (t >> 6); ++w) woff += wsum[w];
  const int excl = x - tsum + woff;

  if (base + 0 < NN) off[base + 0] = excl;
  if (base + 1 < NN) off[base + 1] = excl + v.x;
  if (base + 2 < NN) off[base + 2] = excl + v.x + v.y;
  if (base + 3 < NN) off[base + 3] = excl + v.x + v.y + v.z;
  if (t == 255) bsum[blockIdx.x] = wsum[0] + wsum[1] + wsum[2] + wsum[3];
}

// ---------------------------------------------------------------------------
// K2b-2: exclusive scan of the 98 block sums (in place). 1 block, 128 thr.
// ---------------------------------------------------------------------------
__global__ __launch_bounds__(128) void k_scan2(int* __restrict__ bsum) {
  const int t = threadIdx.x;
  const int v = (t < SCAN_NBLK) ? bsum[t] : 0;
  int x = v;
#pragma unroll
  for (int d = 1; d < 64; d <<= 1) {
    const int y = __shfl_up(x, d, 64);
    if ((t & 63) >= d) x += y;
  }
  __shared__ int ws[2];
  if ((t & 63) == 63) ws[t >> 6] = x;
  __syncthreads();
  const int excl = x - v + ((t >= 64) ? ws[0] : 0);
  if (t < SCAN_NBLK) bsum[t] = excl;
}

// ---------------------------------------------------------------------------
// K2b-3: add block offsets; emit final off + cursor copy; off[NN]=EE.
// ---------------------------------------------------------------------------
__global__ __launch_bounds__(256) void k_scan3(
    const int* __restrict__ bsum, int* __restrict__ off, int* __restrict__ cursor) {
  const int t = threadIdx.x;
  const int base = blockIdx.x * SCAN_CHUNK + t * 4;
  const int add = bsum[blockIdx.x];
  if (base + 3 < NN) {
    int4 v = *reinterpret_cast<const int4*>(&off[base]);
    v.x += add; v.y += add; v.z += add; v.w += add;
    *reinterpret_cast<int4*>(&off[base]) = v;
    *reinterpret_cast<int4*>(&cursor[base]) = v;
  } else {
#pragma unroll
    for (int i = 0; i < 4; ++i)
      if (base + i < NN) {
        const int v = off[base + i] + add;
        off[base + i] = v;
        cursor[base + i] = v;
      }
  }
  if (blockIdx.x == 0 && t == 0) off[NN] = EE;
}

// ---------------------------------------------------------------------------
// K2c: scatter edges into dst-bins (store src index)
// ---------------------------------------------------------------------------
__global__ __launch_bounds__(256) void k_scatter(
    const int* __restrict__ ei, int* __restrict__ cursor, int* __restrict__ ebin) {
  const long e = (long)blockIdx.x * 256 + threadIdx.x;
  const int src = ei[e];
  const int dst = ei[EE + e];
  const int p = atomicAdd(&cursor[dst], 1);
  ebin[p] = src;
}

// ---------------------------------------------------------------------------
// K2d: atomic-free aggregation. One block (128 threads) per dst node.
// ---------------------------------------------------------------------------
__global__ __launch_bounds__(128) void k_aggr(
    const int* __restrict__ off, const int* __restrict__ ebin,
    const float* __restrict__ pos, const float* __restrict__ delta,
    const float* __restrict__ hWf,
    const float* __restrict__ Wf, const float* __restrict__ bf,
    float* __restrict__ aggr) {
  const int n = blockIdx.x;
  const int c = threadIdx.x;
  __shared__ float base[3];
  __shared__ int s_src[128];
  __shared__ float s_rel[128][3];

  if (c < 3) base[c] = delta[(long)n * 3 + c] - pos[(long)n * 3 + c];
  const int s = off[n], e = off[n + 1];

  const float w0 = Wf[0 * 128 + c];
  const float w1 = Wf[1 * 128 + c];
  const float w2 = Wf[2 * 128 + c];
  const float bb = bf[c];
  float acc = 0.f;
  __syncthreads();

  for (int js = s; js < e; js += 128) {
    const int cnt = min(128, e - js);
    if (c < cnt) {
      const int src = ebin[js + c];
      s_src[c] = src;
      s_rel[c][0] = pos[(long)src * 3 + 0] + base[0];
      s_rel[c][1] = pos[(long)src * 3 + 1] + base[1];
      s_rel[c][2] = pos[(long)src * 3 + 2] + base[2];
    }
    __syncthreads();
#pragma unroll 4
    for (int j = 0; j < cnt; ++j) {
      const int src = s_src[j];
      const float hv = hWf[(long)src * CC + c];
      const float m = fmaf(s_rel[j][0], w0,
                      fmaf(s_rel[j][1], w1,
                      fmaf(s_rel[j][2], w2, hv + bb)));
      acc += fmaxf(m, 0.f);
    }
    __syncthreads();
  }
  aggr[(long)n * CC + c] = acc;
}

// ---------------------------------------------------------------------------
// K3: out = leaky( relu(aggr@Wg1+bg1)@Wg2 + bg2 + h ) + column partials.
// 16 rows/block, float4 broadcast LDS reads.
// ---------------------------------------------------------------------------
__global__ __launch_bounds__(128) void k_out(
    const float* __restrict__ aggr,
    const float* __restrict__ Wg1, const float* __restrict__ bg1,
    const float* __restrict__ Wg2, const float* __restrict__ bg2,
    const float* __restrict__ h,
    float* __restrict__ out,
    float* __restrict__ psum, float* __restrict__ psumsq) {
  const int c = threadIdx.x;
  const int rbase = blockIdx.x * 16;
  __shared__ float as_[16][128];      // float4-read: unpadded
  __shared__ float ts[16][128];       // float4-read: unpadded

#pragma unroll
  for (int r = 0; r < 16; ++r)
    as_[r][c] = aggr[(long)(rbase + r) * CC + c];
  __syncthreads();

  float a[16];
#pragma unroll
  for (int r = 0; r < 16; ++r) a[r] = 0.f;
  for (int k = 0; k < 128; k += 4) {
    float w[4];
#pragma unroll
    for (int q = 0; q < 4; ++q) w[q] = Wg1[(k + q) * 128 + c];
#pragma unroll
    for (int r = 0; r < 16; ++r) {
      const float4 v = *reinterpret_cast<const float4*>(&as_[r][k]);
      a[r] = fmaf(v.x, w[0], a[r]);
      a[r] = fmaf(v.y, w[1], a[r]);
      a[r] = fmaf(v.z, w[2], a[r]);
      a[r] = fmaf(v.w, w[3], a[r]);
    }
  }
  const float b1 = bg1[c];
#pragma unroll
  for (int r = 0; r < 16; ++r) ts[r][c] = fmaxf(a[r] + b1, 0.f);
  __syncthreads();

#pragma unroll
  for (int r = 0; r < 16; ++r) a[r] = 0.f;
  for (int k = 0; k < 128; k += 4) {
    float w[4];
#pragma unroll
    for (int q = 0; q < 4; ++q) w[q] = Wg2[(k + q) * 128 + c];
#pragma unroll
    for (int r = 0; r < 16; ++r) {
      const float4 v = *reinterpret_cast<const float4*>(&ts[r][k]);
      a[r] = fmaf(v.x, w[0], a[r]);
      a[r] = fmaf(v.y, w[1], a[r]);
      a[r] = fmaf(v.z, w[2], a[r]);
      a[r] = fmaf(v.w, w[3], a[r]);
    }
  }

  const float b2 = bg2[c];
  float lsum = 0.f, lsq = 0.f;
#pragma unroll
  for (int r = 0; r < 16; ++r) {
    float o = a[r] + b2 + h[(long)(rbase + r) * CC + c];
    o = (o >= 0.f) ? o : 0.2f * o;
    out[(long)(rbase + r) * CC + c] = o;
    lsum += o;
    lsq = fmaf(o, o, lsq);
  }
  const int slot = blockIdx.x & 63;
  atomicAdd(&psum[slot * 128 + c], lsum);
  atomicAdd(&psumsq[slot * 128 + c], lsq);
}

// ---------------------------------------------------------------------------
// K4: reduce 64 partial slots -> mu, inv_std  (1 block, 128 threads)
// ---------------------------------------------------------------------------
__global__ __launch_bounds__(128) void k_stats(
    const float* __restrict__ psum, const float* __restrict__ psumsq,
    float* __restrict__ mu, float* __restrict__ inv) {
  const int c = threadIdx.x;
  float s = 0.f, q = 0.f;
  for (int i = 0; i < 64; ++i) {
    s += psum[i * 128 + c];
    q += psumsq[i * 128 + c];
  }
  const float m = s / (float)NN;
  const float v = q / (float)NN - m * m;
  mu[c] = m;
  inv[c] = rsqrtf(v + LN_EPS);
}

// ---------------------------------------------------------------------------
// K5: s = style@Ws + bs; out = gamma*(out-mu)*inv + beta  (in-place)
// 16 rows/block, 256 threads, float4 broadcast LDS reads.
// ---------------------------------------------------------------------------
__global__ __launch_bounds__(256) void k_final(
    const float* __restrict__ style,
    const float* __restrict__ Ws, const float* __restrict__ bs,
    const float* __restrict__ mu, const float* __restrict__ inv,
    float* __restrict__ out) {
  const int t = threadIdx.x;          // 0..255
  const int rbase = blockIdx.x * 16;
  __shared__ float ss[16][128];       // float4-read: unpadded
  __shared__ float sm[16][256];

#pragma unroll
  for (int i = 0; i < 8; ++i) {       // 2048 style elems / 256 threads
    const int idx = t + 256 * i;
    const int r = idx >> 7, k = idx & 127;
    ss[r][k] = style[(long)(rbase + r) * 128 + k];
  }
  __syncthreads();

  float a[16];
#pragma unroll
  for (int r = 0; r < 16; ++r) a[r] = 0.f;
  for (int k = 0; k < 128; k += 4) {
    float w[4];
#pragma unroll
    for (int q = 0; q < 4; ++q) w[q] = Ws[(k + q) * 256 + t];
#pragma unroll
    for (int r = 0; r < 16; ++r) {
      const float4 v = *reinterpret_cast<const float4*>(&ss[r][k]);
      a[r] = fmaf(v.x, w[0], a[r]);
      a[r] = fmaf(v.y, w[1], a[r]);
      a[r] = fmaf(v.z, w[2], a[r]);
      a[r] = fmaf(v.w, w[3], a[r]);
    }
  }
  const float b = bs[t];
#pragma unroll
  for (int r = 0; r < 16; ++r) sm[r][t] = a[r] + b;
  __syncthreads();

#pragma unroll
  for (int i = 0; i < 8; ++i) {       // 2048 output elems / 256 threads
    const int idx = t + 256 * i;
    const int r = idx >> 7, c = idx & 127;
    const long g = (long)(rbase + r) * CC + c;
    const float o = out[g];
    out[g] = sm[r][c] * ((o - mu[c]) * inv[c]) + sm[r][128 + c];
  }
}

// ---------------------------------------------------------------------------
extern "C" void kernel_launch(void* const* d_in, const int* in_sizes, int n_in,
                              void* d_out, int out_size, void* d_ws, size_t ws_size,
                              hipStream_t stream) {
  const float* h     = (const float*)d_in[0];
  const float* pos   = (const float*)d_in[1];
  const float* style = (const float*)d_in[2];
  const int*   ei    = (const int*)  d_in[3];
  const float* Wh1   = (const float*)d_in[4];
  const float* bh1   = (const float*)d_in[5];
  const float* Wh2   = (const float*)d_in[6];
  const float* bh2   = (const float*)d_in[7];
  const float* Wf    = (const float*)d_in[8];
  const float* bf    = (const float*)d_in[9];
  const float* Wg1   = (const float*)d_in[10];
  const float* bg1   = (const float*)d_in[11];
  const float* Wg2   = (const float*)d_in[12];
  const float* bg2   = (const float*)d_in[13];
  const float* Ws    = (const float*)d_in[14];
  const float* bs    = (const float*)d_in[15];
  float* out = (float*)d_out;

  // workspace layout (floats / ints) — all segments 16B-aligned
  float* ws     = (float*)d_ws;
  float* hWf    = ws;                          // N*128
  float* aggr   = hWf + (long)NN * CC;         // N*128
  float* delta  = aggr + (long)NN * CC;        // N*3
  float* psum   = delta + (long)NN * 3;        // 64*128
  float* psumsq = psum + 64 * 128;             // 64*128
  float* mu     = psumsq + 64 * 128;           // 128
  float* inv    = mu + 128;                    // 128
  int*   deg    = (int*)(inv + 128);           // N
  int*   off    = deg + NN;                    // N+1 (padded to N+4)
  int*   cursor = off + NN + 4;                // N
  int*   ebin   = cursor + NN;                 // E
  int*   bsum   = ebin + EE;                   // SCAN_NBLK (98), pad 128

  hipMemsetAsync(deg, 0, (size_t)NN * sizeof(int), stream);
  hipMemsetAsync(psum, 0, (size_t)(64 * 128 * 2) * sizeof(float), stream);

  k_node<<<NN / 16, 128, 0, stream>>>(h, Wh1, bh1, Wh2, bh2, Wf, hWf, delta);
  k_count<<<EE / 256, 256, 0, stream>>>(ei, deg);
  k_scan1<<<SCAN_NBLK, 256, 0, stream>>>(deg, off, bsum);
  k_scan2<<<1, 128, 0, stream>>>(bsum);
  k_scan3<<<SCAN_NBLK, 256, 0, stream>>>(bsum, off, cursor);
  k_scatter<<<EE / 256, 256, 0, stream>>>(ei, cursor, ebin);
  k_aggr<<<NN, 128, 0, stream>>>(off, ebin, pos, delta, hWf, Wf, bf, aggr);
  k_out<<<NN / 16, 128, 0, stream>>>(aggr, Wg1, bg1, Wg2, bg2, h, out, psum, psumsq);
  k_stats<<<1, 128, 0, stream>>>(psum, psumsq, mu, inv);
  k_final<<<NN / 16, 256, 0, stream>>>(style, Ws, bs, mu, inv, out);
}